// Round 5
// baseline (145.482 us; speedup 1.0000x reference)
//
#include <hip/hip_runtime.h>
#include <hip/hip_bf16.h>

// N=2, L=8192, dim=256, H=8, Pd=32. seg = n*8+h (16 segs of 8192 rows).
// K1 k_prepw: Wq/Wv/Wk fp32 -> bf16 MFMA-fragment order (tiny, <1us).
// K2 k_gemm : register-resident fused GEMM, 32 rows/block, grid 512.
//             A-fragments read directly from fp32 Y/X (coalesced 128B/16rows)
//             with inline bf16 cvt. q-pass then fused v+k pass (low VGPR,
//             no k-loop barriers, no spills). c/cden via shuffles; 32-row
//             tile totals to `tot`; pk stored bf16.
// K3 k_scan : per-block inline prefix over `tot` (no separate offset kernel),
//             serial 64-row walk per wave, num/den paired via shfl_xor(32).
// ws floats: Wf[bf16 196608] = 98304 | pk[bf16 4194304] = 2097152 |
//            c 131072 | cd 131072 | tot 16*256*64 = 262144   (~10.4 MB)

typedef __attribute__((ext_vector_type(8))) short short8;  // 8 bf16
typedef __attribute__((ext_vector_type(4))) float f32x4;

__device__ __forceinline__ float phi_f(float x) {
    return x > 0.f ? x + 1.f : __expf(x);   // elu(x)+1
}
__device__ __forceinline__ unsigned short f2bf(float x) {
    __hip_bfloat16 h = __float2bfloat16(x);   // RNE
    return *reinterpret_cast<unsigned short*>(&h);
}
__device__ __forceinline__ float bf2f(unsigned short u) {
    return __uint_as_float(((unsigned int)u) << 16);
}
__device__ __forceinline__ short8 cvt8(float4 f0, float4 f1) {
    short8 o;
    o[0] = f2bf(f0.x); o[1] = f2bf(f0.y); o[2] = f2bf(f0.z); o[3] = f2bf(f0.w);
    o[4] = f2bf(f1.x); o[5] = f2bf(f1.y); o[6] = f2bf(f1.z); o[7] = f2bf(f1.w);
    return o;
}

// ---------------- K1: W -> bf16 fragment order ----------------------------
// chunk cc (per mat): ln=cc&15, qd=(cc>>4)&3, kt=(cc>>6)&7, jt=cc>>9.
// src elems: (col=jt*16+ln, k=kt*32+qd*8 .. +7). 24576 chunks total.
__global__ __launch_bounds__(256) void k_prepw(
        const float* __restrict__ Wq, const float* __restrict__ Wk,
        const float* __restrict__ Wv, unsigned short* __restrict__ Wf)
{
    const int g = blockIdx.x * 256 + threadIdx.x;   // 0..24575
    const int mat = g >> 13, cc = g & 8191;         // 0=q, 1=v, 2=k
    const float* src = (mat == 0) ? Wq : (mat == 1 ? Wv : Wk);
    const int ln = cc & 15, qd = (cc >> 4) & 3, kt = (cc >> 6) & 7, jt = cc >> 9;
    const float* s = src + (size_t)(jt * 16 + ln) * 256 + kt * 32 + qd * 8;
    *(short8*)(Wf + (size_t)g * 8) = cvt8(*(const float4*)s, *(const float4*)(s + 4));
}

// ---------------- K2: register-resident fused GEMM ------------------------
// grid 512 (32 rows each), block 256 (4 waves; wave w = cols w*64..+63
// = heads 2w, 2w+1). No barriers in the k-loops.
__global__ __launch_bounds__(256, 2) void k_gemm(
        const float* __restrict__ Y, const float* __restrict__ X,
        const unsigned short* __restrict__ Wf,
        unsigned short* __restrict__ pk_out,
        float* __restrict__ c_out, float* __restrict__ cd_out,
        float* __restrict__ tot)
{
    __shared__ float scc[32][8], scd[32][8];
    __shared__ __align__(16) unsigned short spk[32 * 264];

    const int rb = blockIdx.x;            // rows 32rb..32rb+31
    const int n = rb >> 8;
    const int tile = rb & 255;            // 32-row tile index within segment
    const int lseg0 = tile * 32;
    const bool hasprev = (tile != 0);
    const int t = threadIdx.x, w = t >> 6, lane = t & 63;
    const int ln = lane & 15, qd = lane >> 4;
    const int fl = qd * 16 + ln;

    const short8* W8 = (const short8*)Wf;
    const int rt0 = rb * 2;
    const int rtp = hasprev ? rt0 - 1 : 0;        // clamped; unused at seg start

    // direct fp32 A-fragment load: row = rowtile*16+ln, k = kt*32+qd*8..+7
    const float* Yp  = Y + (size_t)(rtp * 16 + ln) * 256 + qd * 8;
    const float* Y0  = Y + (size_t)(rt0 * 16 + ln) * 256 + qd * 8;
    const float* Y1  = Y0 + 16 * 256;
    const float* X0  = X + (size_t)(rt0 * 16 + ln) * 256 + qd * 8;
    const float* X1  = X0 + 16 * 256;

    // ---- q pass: aq (2 row-tiles) + aqp (boundary tile) ----
    f32x4 aq[2][4], aqp[4];
#pragma unroll
    for (int j = 0; j < 4; ++j) {
        aq[0][j] = (f32x4){0.f, 0.f, 0.f, 0.f};
        aq[1][j] = (f32x4){0.f, 0.f, 0.f, 0.f};
        aqp[j]   = (f32x4){0.f, 0.f, 0.f, 0.f};
    }
    for (int kt = 0; kt < 8; ++kt) {
        const int ko = kt * 32;
        short8 ayp = cvt8(*(const float4*)(Yp + ko), *(const float4*)(Yp + ko + 4));
        short8 ay0 = cvt8(*(const float4*)(Y0 + ko), *(const float4*)(Y0 + ko + 4));
        short8 ay1 = cvt8(*(const float4*)(Y1 + ko), *(const float4*)(Y1 + ko + 4));
#pragma unroll
        for (int j = 0; j < 4; ++j) {
            short8 b = W8[(size_t)(((0 * 16 + w * 4 + j) * 8 + kt) * 4) * 16 + fl];
            aqp[j]   = __builtin_amdgcn_mfma_f32_16x16x32_bf16(ayp, b, aqp[j], 0, 0, 0);
            aq[0][j] = __builtin_amdgcn_mfma_f32_16x16x32_bf16(ay0, b, aq[0][j], 0, 0, 0);
            aq[1][j] = __builtin_amdgcn_mfma_f32_16x16x32_bf16(ay1, b, aq[1][j], 0, 0, 0);
        }
    }
#pragma unroll
    for (int i = 0; i < 2; ++i)
#pragma unroll
        for (int j = 0; j < 4; ++j)
#pragma unroll
            for (int r = 0; r < 4; ++r) aq[i][j][r] = phi_f(aq[i][j][r]);
    float pprev[4];
#pragma unroll
    for (int j = 0; j < 4; ++j) {
        float p15 = __shfl(aqp[j][3], 48 + ln);   // row 15 of boundary tile
        pprev[j] = hasprev ? phi_f(p15) : 0.f;
    }

    // ---- fused v + k pass (shares X fragment loads) ----
    f32x4 av[2][4], ak[2][4];
#pragma unroll
    for (int i = 0; i < 2; ++i)
#pragma unroll
        for (int j = 0; j < 4; ++j) {
            av[i][j] = (f32x4){0.f, 0.f, 0.f, 0.f};
            ak[i][j] = (f32x4){0.f, 0.f, 0.f, 0.f};
        }
    for (int kt = 0; kt < 8; ++kt) {
        const int ko = kt * 32;
        short8 ax0 = cvt8(*(const float4*)(X0 + ko), *(const float4*)(X0 + ko + 4));
        short8 ax1 = cvt8(*(const float4*)(X1 + ko), *(const float4*)(X1 + ko + 4));
#pragma unroll
        for (int j = 0; j < 4; ++j) {
            short8 bv = W8[(size_t)(((1 * 16 + w * 4 + j) * 8 + kt) * 4) * 16 + fl];
            short8 bk = W8[(size_t)(((2 * 16 + w * 4 + j) * 8 + kt) * 4) * 16 + fl];
            av[0][j] = __builtin_amdgcn_mfma_f32_16x16x32_bf16(ax0, bv, av[0][j], 0, 0, 0);
            av[1][j] = __builtin_amdgcn_mfma_f32_16x16x32_bf16(ax1, bv, av[1][j], 0, 0, 0);
            ak[0][j] = __builtin_amdgcn_mfma_f32_16x16x32_bf16(ax0, bk, ak[0][j], 0, 0, 0);
            ak[1][j] = __builtin_amdgcn_mfma_f32_16x16x32_bf16(ax1, bk, ak[1][j], 0, 0, 0);
        }
    }

    // ---- c, cden per (row, head): dpq chain via shuffles ----
    float cc_[2][2][4], cd_[2][2][4];
#pragma unroll
    for (int i = 0; i < 2; ++i)
#pragma unroll
        for (int jh = 0; jh < 2; ++jh)
#pragma unroll
            for (int r = 0; r < 4; ++r) { cc_[i][jh][r] = 0.f; cd_[i][jh][r] = 0.f; }
#pragma unroll
    for (int j = 0; j < 4; ++j) {
        const int jh = j >> 1;
        float carry = pprev[j];
#pragma unroll
        for (int i = 0; i < 2; ++i) {
            const float p0 = aq[i][j][0], p1 = aq[i][j][1], p2 = aq[i][j][2], p3 = aq[i][j][3];
            const float up3 = __shfl_up(p3, 16);
            const float prev0 = (qd == 0) ? carry : up3;
            const float d0 = p0 - prev0, d1 = p1 - p0, d2 = p2 - p1, d3 = p3 - p2;
            cc_[i][jh][0] += d0 * av[i][j][0]; cd_[i][jh][0] += d0;
            cc_[i][jh][1] += d1 * av[i][j][1]; cd_[i][jh][1] += d1;
            cc_[i][jh][2] += d2 * av[i][j][2]; cd_[i][jh][2] += d2;
            cc_[i][jh][3] += d3 * av[i][j][3]; cd_[i][jh][3] += d3;
            carry = __shfl(p3, ln + 48);
        }
    }
#pragma unroll
    for (int i = 0; i < 2; ++i)
#pragma unroll
        for (int jh = 0; jh < 2; ++jh)
#pragma unroll
            for (int r = 0; r < 4; ++r) {
                float x = cc_[i][jh][r];
                x += __shfl_xor(x, 1); x += __shfl_xor(x, 2);
                x += __shfl_xor(x, 4); x += __shfl_xor(x, 8);
                float y = cd_[i][jh][r];
                y += __shfl_xor(y, 1); y += __shfl_xor(y, 2);
                y += __shfl_xor(y, 4); y += __shfl_xor(y, 8);
                if (ln == 0) {
                    scc[i * 16 + qd * 4 + r][2 * w + jh] = x;
                    scd[i * 16 + qd * 4 + r][2 * w + jh] = y;
                }
            }
    __syncthreads();
    {
        const int row = t & 31, h = t >> 5;
        const size_t gi = (size_t)(n * 8 + h) * 8192 + lseg0 + row;
        c_out[gi]  = scc[row][h];
        cd_out[gi] = scd[row][h];
    }

    // ---- phi on k, 32-row tile totals ----
#pragma unroll
    for (int i = 0; i < 2; ++i)
#pragma unroll
        for (int j = 0; j < 4; ++j)
#pragma unroll
            for (int r = 0; r < 4; ++r) ak[i][j][r] = phi_f(ak[i][j][r]);
#pragma unroll
    for (int j = 0; j < 4; ++j) {
        const int head = 2 * w + (j >> 1);
        float tn = 0.f, td = 0.f;
#pragma unroll
        for (int i = 0; i < 2; ++i)
#pragma unroll
            for (int r = 0; r < 4; ++r) {
                const int row = i * 16 + qd * 4 + r;
                const float pv = ak[i][j][r];
                tn += scc[row][head] * pv;
                td += scd[row][head] * pv;
            }
        tn += __shfl_xor(tn, 16); tn += __shfl_xor(tn, 32);
        td += __shfl_xor(td, 16); td += __shfl_xor(td, 32);
        if (qd == 0) {
            const int d = (j & 1) * 16 + ln;
            const size_t bi = ((size_t)(n * 8 + head) * 256 + tile) * 64;
            tot[bi + d]      = tn;
            tot[bi + 32 + d] = td;
        }
    }

    // ---- pk -> global bf16 via LDS transpose ----
#pragma unroll
    for (int i = 0; i < 2; ++i)
#pragma unroll
        for (int j = 0; j < 4; ++j)
#pragma unroll
            for (int r = 0; r < 4; ++r)
                spk[(i * 16 + qd * 4 + r) * 264 + w * 64 + j * 16 + ln] = f2bf(ak[i][j][r]);
    __syncthreads();
#pragma unroll
    for (int it = 0; it < 4; ++it) {
        const int idx = t + 256 * it;     // 1024 chunks (32 rows x 32 col-groups)
        const int row = idx >> 5, cg = idx & 31;
        short8 vals = *(const short8*)&spk[row * 264 + cg * 8];
        const int head = cg >> 2, d8 = (cg & 3) * 8;
        *(short8*)(pk_out + ((size_t)(n * 8 + head) * 8192 + lseg0 + row) * 32 + d8) = vals;
    }
}

// ---------------- K3: inline prefix + scan + divide + store ---------------
// grid 512 = 16 segs x 32 blocks (256 rows); wave wv owns 64 rows.
__global__ __launch_bounds__(256) void k_scan(
        const unsigned short* __restrict__ pk, const float* __restrict__ c,
        const float* __restrict__ cd, const float* __restrict__ tot,
        float* __restrict__ out)
{
    __shared__ __align__(16) unsigned short spk[256 * 32];  // 16 KB bf16
    __shared__ float sc[256], sd[256];
    __shared__ float wsum[4][64];

    const int bx = blockIdx.x, seg = bx >> 5, blk = bx & 31;
    const int n = seg >> 3, h = seg & 7;
    const int t = threadIdx.x, l0 = blk * 256;
    const int wv = t >> 6, lane = t & 63;

    // prefix over the blk*8 preceding 32-row tiles, 4-way split across waves
    float pre = 0.f;
    const int T = blk * 8;
    for (int i = wv; i < T; i += 4)
        pre += tot[((size_t)seg * 256 + i) * 64 + lane];
    wsum[wv][lane] = pre;

#pragma unroll
    for (int i = 0; i < 4; ++i) {
        const int idx = t + 256 * i;      // 1024 short8 chunks; layouts identical
        *(short8*)&spk[idx * 8] = *(const short8*)(pk + ((size_t)seg * 8192 + l0) * 32 + idx * 8);
    }
    sc[t] = c[(size_t)seg * 8192 + l0 + t];
    sd[t] = cd[(size_t)seg * 8192 + l0 + t];
    __syncthreads();

    float run = wsum[0][lane] + wsum[1][lane] + wsum[2][lane] + wsum[3][lane];
    for (int i = 0; i < 2 * wv; ++i)      // own-block tiles before this wave
        run += tot[((size_t)seg * 256 + T + i) * 64 + lane];

    const int d = lane & 31, part = lane >> 5;
    const float* coefs = part ? sd : sc;
    float* obase = out + ((size_t)n * 8192 + l0 + wv * 64) * 256 + h * 32 + d;

#pragma unroll
    for (int p = 0; p < 64; ++p) {
        const int m = wv * 64 + p;
        run += coefs[m] * bf2f(spk[m * 32 + d]);
        const float other = __shfl_xor(run, 32);   // pair num<->den
        if (!part) obase[(size_t)p * 256] = run / other;
    }
}

extern "C" void kernel_launch(void* const* d_in, const int* in_sizes, int n_in,
                              void* d_out, int out_size, void* d_ws, size_t ws_size,
                              hipStream_t stream)
{
    const float* Y  = (const float*)d_in[0];
    const float* X  = (const float*)d_in[1];
    const float* Wq = (const float*)d_in[2];
    const float* Wk = (const float*)d_in[3];
    const float* Wv = (const float*)d_in[4];
    float* out = (float*)d_out;

    float* ws = (float*)d_ws;
    unsigned short* Wf = (unsigned short*)ws;                 // 196608 bf16
    unsigned short* pk = (unsigned short*)(ws + 98304);       // 4194304 bf16
    float* c   = ws + 98304 + 2097152;
    float* cd  = c  + 131072;
    float* tot = cd + 131072;    // 16*256*64

    hipLaunchKernelGGL(k_prepw, dim3(96),  dim3(256), 0, stream, Wq, Wk, Wv, Wf);
    hipLaunchKernelGGL(k_gemm,  dim3(512), dim3(256), 0, stream,
                       Y, X, Wf, pk, c, cd, tot);
    hipLaunchKernelGGL(k_scan,  dim3(512), dim3(256), 0, stream, pk, c, cd, tot, out);
}